// Round 16
// baseline (50.749 us; speedup 1.0000x reference)
//
#include <hip/hip_runtime.h>

// NetVLAD fused via bf16 MFMA, two-stage, single-chunk 512-thread blocks.
// R16 = R15 skeleton (5 barriers, 40.3 KB LDS, OOB-safe) on 8 waves:
// acc 64->32 regs/thread (unified VGPR+AGPR was the occupancy cap, not LDS).
//   s = x·W, a = softmax_k(s), v = a^T x + (sum a)·C
// x: [64,784,512] f32, W/C: [512,32] f32, out: [64, 512*32] f32
#define NB 64
#define HW 784
#define DD 512
#define KK 32
#define BPB 28            // blocks per batch (28 px each: 28*28 = 784 = HW)
#define PPB 28            // valid pixels per block
#define SLOTS 32          // logical px slots in MFMA (28 valid + 4 masked a=0)

typedef __attribute__((ext_vector_type(8))) short bf16x8;   // 8 bf16 (4 VGPR)
typedef __attribute__((ext_vector_type(4))) float f32x4;    // MFMA 16x16 acc
typedef __attribute__((ext_vector_type(4))) unsigned short u16x4;

// ws: bf16 partials [NB*BPB][8 waves][8 frags][64 lanes] u16x4 (8 B each),
//     then fp32 asums [NB*BPB][KK]
#define NBLK (NB * BPB)
#define PART_BYTES ((size_t)NBLK * 8 * 8 * 64 * 8)
#define WS_NEED    (PART_BYTES + (size_t)NBLK * KK * 4)

__device__ __forceinline__ unsigned short f2bf(float f) {
    unsigned u = __float_as_uint(f);
    u += 0x7fffu + ((u >> 16) & 1u);      // round-to-nearest-even
    return (unsigned short)(u >> 16);
}
__device__ __forceinline__ float bf2f(unsigned short u) {
    return __uint_as_float((unsigned)u << 16);
}
// packed f32x2 -> bf16x2, one instruction (lo = a, hi = b; T12 recipe)
__device__ __forceinline__ unsigned cvtpk(float a, float b) {
    unsigned r;
    asm("v_cvt_pk_bf16_f32 %0, %1, %2" : "=v"(r) : "v"(a), "v"(b));
    return r;
}

template <bool USE_WS>
__global__ __launch_bounds__(512) void netvlad_stage1(
    const float* __restrict__ x, const float* __restrict__ Wg,
    const float* __restrict__ Cg, float* __restrict__ out,
    void* __restrict__ ws)
{
    // LDS 40,256 B (identical to R15) -> 4 blocks/CU feasible; 8 waves/block
    __shared__ __align__(16) unsigned short xs[28 * 520];      // 29,120 B bf16
    __shared__ unsigned short spart[4][SLOTS][33];             // 8,448 B bf16 partials
    __shared__ __align__(16) unsigned short aTe[KK * 40];      // a^T [k][px] 2,560 B
    __shared__ float asumF[KK];

    const int tid = threadIdx.x;
    const int l   = tid & 63, w = tid >> 6;      // lane, wave 0..7
    const int l15 = l & 15,  lq = l >> 4;        // frag row/col, quarter
    const int d4  = w & 3;                        // phase-A d-slice 128*d4
    const int mtw = w >> 2;                       // phase-A px-half (16 px)
    const int k   = tid & 31, pg = tid >> 5;     // softmax mapping: pg 0..15
    const int bid = blockIdx.x;
    const int b   = bid / BPB;
    const int pb  = (bid % BPB) * PPB;
    const float* xb = x + (size_t)b * HW * DD;

    // Zero-init spart: phases A/C deliberately read past xs into this region
    // (rows 28-31); every reachable byte must be finite. 2112 dwords.
    {
        unsigned* sz = (unsigned*)spart;
#pragma unroll
        for (int i = 0; i < 4; ++i) sz[tid + 512*i] = 0u;
        if (tid < 2112 - 2048) sz[2048 + tid] = 0u;
    }

    // W B-frags: Wf[ks][nt] lane holds W[d = d4*128+ks*32+lq*8+j][nt*16+l15]
    bf16x8 Wf[4][2];
#pragma unroll
    for (int ks = 0; ks < 4; ++ks)
#pragma unroll
        for (int nt = 0; nt < 2; ++nt)
#pragma unroll
            for (int j = 0; j < 8; ++j)
                Wf[ks][nt][j] = (short)f2bf(Wg[(d4*128 + ks*32 + lq*8 + j) * KK + nt*16 + l15]);

    // phase-C acc: wave owns d-slice [64w,64w+64): k = mt*16+lq*4+jj, d = 64w+nt*16+l15
    f32x4 acc[2][4];
#pragma unroll
    for (int mt = 0; mt < 2; ++mt)
#pragma unroll
        for (int nt = 0; nt < 4; ++nt)
#pragma unroll
            for (int jj = 0; jj < 4; ++jj) acc[mt][nt][jj] = 0.f;
    float asum_part = 0.f;

    // ---- stage: 28 px * 512 f32 -> bf16 LDS; 7 float4/thread, no clamp ----
    {
        float4 r[7];
#pragma unroll
        for (int j = 0; j < 7; ++j) {
            const int f = tid + 512*j, row = f >> 7, c4 = f & 127;
            r[j] = *(const float4*)(xb + (size_t)(pb + row) * DD + c4*4);
        }
#pragma unroll
        for (int j = 0; j < 7; ++j) {
            const int f = tid + 512*j, row = f >> 7, c4 = f & 127;
            uint2 pk = make_uint2(cvtpk(r[j].x, r[j].y), cvtpk(r[j].z, r[j].w));
            *(uint2*)&xs[row*520 + c4*4] = pk;
        }
    }
    __syncthreads();

    // ---- phase A: s[16px(mtw)][32k] partial over d-slice 128*d4 (8 MFMA) ----
    {
        f32x4 sp[2];
#pragma unroll
        for (int nt = 0; nt < 2; ++nt)
#pragma unroll
            for (int jj = 0; jj < 4; ++jj) sp[nt][jj] = 0.f;
#pragma unroll
        for (int ks = 0; ks < 4; ++ks) {
            const bf16x8 af = *(const bf16x8*)&xs[(mtw*16 + l15)*520 + d4*128 + ks*32 + lq*8];
#pragma unroll
            for (int nt = 0; nt < 2; ++nt)
                sp[nt] = __builtin_amdgcn_mfma_f32_16x16x32_bf16(
                    af, Wf[ks][nt], sp[nt], 0, 0, 0);
        }
        // bf16 store; rows p>=28 (mtw==1 && lq==3) forced 0 (masked px)
#pragma unroll
        for (int nt = 0; nt < 2; ++nt)
#pragma unroll
            for (int jj = 0; jj < 4; ++jj) {
                unsigned short v = f2bf(sp[nt][jj]);
                if (mtw == 1 && lq == 3) v = 0;
                spart[d4][mtw*16 + lq*4 + jj][nt*16 + l15] = v;
            }
    }
    __syncthreads();

    // ---- phase B: softmax over k; thread (pg,k), px = pg + 16i ----
#pragma unroll
    for (int i = 0; i < 2; ++i) {
        const int p = pg + 16*i;
        const float s = bf2f(spart[0][p][k]) + bf2f(spart[1][p][k])
                      + bf2f(spart[2][p][k]) + bf2f(spart[3][p][k]);
        const float e = __expf(s);
        float su = e;
#pragma unroll
        for (int msk = 16; msk >= 1; msk >>= 1)
            su += __shfl_xor(su, msk);
        const float a = (p < PPB) ? e * __builtin_amdgcn_rcpf(su) : 0.f;
        asum_part += a;
        aTe[k*40 + p] = f2bf(a);
    }
    __syncthreads();

    // ---- phase C: v^T[32k][64d-slice] += a^T[32k][32px] · x[32px][d] (8 MFMA)
    //      (rows 28-31 overrun into zero-inited/finite spart; a=0 there) ----
    {
        bf16x8 afr[2];
#pragma unroll
        for (int mt = 0; mt < 2; ++mt)
            afr[mt] = *(const bf16x8*)&aTe[(mt*16 + l15)*40 + lq*8];
#pragma unroll
        for (int nt = 0; nt < 4; ++nt) {
            const int d = w*64 + nt*16 + l15;
            bf16x8 bfr;
#pragma unroll
            for (int j = 0; j < 8; ++j) {                  // column read of x, j rotated
                const int jj = (j + 2*lq) & 7;             // per-quarter bank stagger
                bfr[jj] = (short)xs[(lq*8 + jj)*520 + d];
            }
#pragma unroll
            for (int mt = 0; mt < 2; ++mt)
                acc[mt][nt] = __builtin_amdgcn_mfma_f32_16x16x32_bf16(
                    afr[mt], bfr, acc[mt][nt], 0, 0, 0);
        }
    }
    __syncthreads();

    // ---- block asum[k] reduce (ared aliases aTe: dead after phase C) ----
    float* ared = (float*)aTe;     // [16][32] = 2048 B <= 2560 B
    ared[pg*KK + k] = asum_part;
    __syncthreads();
    float* wsA = (float*)((char*)ws + PART_BYTES);
    if (tid < KK) {
        float s = 0.f;
#pragma unroll
        for (int g = 0; g < 16; ++g) s += ared[g*KK + tid];
        if (USE_WS) wsA[(size_t)bid * KK + tid] = s;
        else        asumF[tid] = s;
    }

    if (USE_WS) {
        // bf16 partial store, thread-major: coalesced 8B streaming (cvt_pk packed)
        u16x4* o = (u16x4*)ws + ((size_t)bid * 8 + w) * (8 * 64);
#pragma unroll
        for (int mt = 0; mt < 2; ++mt)
#pragma unroll
            for (int nt = 0; nt < 4; ++nt) {
                uint2 pk = make_uint2(cvtpk(acc[mt][nt][0], acc[mt][nt][1]),
                                      cvtpk(acc[mt][nt][2], acc[mt][nt][3]));
                *(uint2*)&o[(mt*4 + nt)*64 + l] = pk;
            }
    } else {
        __syncthreads();
        float* ob = out + (size_t)b * (DD * KK);
#pragma unroll
        for (int mt = 0; mt < 2; ++mt)
#pragma unroll
            for (int nt = 0; nt < 4; ++nt)
#pragma unroll
                for (int jj = 0; jj < 4; ++jj) {
                    const int kk = mt*16 + lq*4 + jj;
                    const int d  = w*64 + nt*16 + l15;
                    atomicAdd(&ob[d*KK + kk], acc[mt][nt][jj] + asumF[kk] * Cg[d*KK + kk]);
                }
    }
}

// Stage 2: block = (b, 128-d slice jsl): sum 28 bf16 partials, add asum*C, write
// (R8-verified indexing: jsl covers stage1 waves {2jsl, 2jsl+1})
__global__ __launch_bounds__(256) void netvlad_stage2(
    const void* __restrict__ ws, const float* __restrict__ Cg,
    float* __restrict__ out)
{
    __shared__ float lds[128 * 33];    // canonical [d_local][k], padded
    __shared__ float asumT[KK];

    const int t = threadIdx.x;
    const int b = blockIdx.x >> 2;
    const int jsl = blockIdx.x & 3;

    const float* wsA = (const float*)((const char*)ws + PART_BYTES);
    if (t < KK) {
        float s = 0.f;
#pragma unroll
        for (int p = 0; p < BPB; ++p)
            s += wsA[(size_t)(b*BPB + p) * KK + t];
        asumT[t] = s;
    }

    const u16x4* wsp = (const u16x4*)ws;
    float4 v[4];
#pragma unroll
    for (int i = 0; i < 4; ++i) v[i] = make_float4(0.f, 0.f, 0.f, 0.f);
    for (int p = 0; p < BPB; ++p) {
        const size_t base = (size_t)(b*BPB + p) * 8 * (8 * 64);
#pragma unroll
        for (int i = 0; i < 4; ++i) {
            const int flat = t + 256*i;           // (w2, fr, lane)
            const int g = flat >> 6, lane = flat & 63;
            const int w2 = g >> 3, fr = g & 7;
            const u16x4 u = wsp[base + ((size_t)(2*jsl + w2) * 8 + fr)*64 + lane];
            v[i].x += bf2f(u[0]); v[i].y += bf2f(u[1]);
            v[i].z += bf2f(u[2]); v[i].w += bf2f(u[3]);
        }
    }
    // scatter frag layout -> canonical [d_local][k]
#pragma unroll
    for (int i = 0; i < 4; ++i) {
        const int flat = t + 256*i;
        const int g = flat >> 6, lane = flat & 63;
        const int w2 = g >> 3, fr = g & 7;
        const int mt = fr >> 2, nt = fr & 3;
        const int q = lane >> 4, r15 = lane & 15;
        const int dl = w2*64 + nt*16 + r15;
        const int kb = mt*16 + q*4;
        lds[dl*33 + kb + 0] = v[i].x;
        lds[dl*33 + kb + 1] = v[i].y;
        lds[dl*33 + kb + 2] = v[i].z;
        lds[dl*33 + kb + 3] = v[i].w;
    }
    __syncthreads();

    float* outw = out + (size_t)b * (DD*KK) + jsl * 128 * KK;
    const float* Cw = Cg + jsl * 128 * KK;
#pragma unroll
    for (int i = 0; i < 4; ++i) {
        const int o4 = t + 256*i;
        const int dl = o4 >> 3, kq = (o4 & 7) * 4;
        const float4 c4 = *(const float4*)&Cw[dl*KK + kq];
        float4 rr;
        rr.x = lds[dl*33 + kq + 0] + asumT[kq + 0] * c4.x;
        rr.y = lds[dl*33 + kq + 1] + asumT[kq + 1] * c4.y;
        rr.z = lds[dl*33 + kq + 2] + asumT[kq + 2] * c4.z;
        rr.w = lds[dl*33 + kq + 3] + asumT[kq + 3] * c4.w;
        ((float4*)outw)[o4] = rr;
    }
}

extern "C" void kernel_launch(void* const* d_in, const int* in_sizes, int n_in,
                              void* d_out, int out_size, void* d_ws, size_t ws_size,
                              hipStream_t stream) {
    const float* x = (const float*)d_in[0];
    const float* W = (const float*)d_in[1];
    const float* C = (const float*)d_in[2];
    float* out = (float*)d_out;

    if (ws_size >= WS_NEED) {
        netvlad_stage1<true><<<dim3(NBLK), dim3(512), 0, stream>>>(x, W, C, out, d_ws);
        netvlad_stage2<<<dim3(NB * 4), dim3(256), 0, stream>>>(d_ws, C, out);
    } else {
        hipMemsetAsync(out, 0, (size_t)out_size * sizeof(float), stream);
        netvlad_stage1<false><<<dim3(NBLK), dim3(512), 0, stream>>>(x, W, C, out, d_ws);
    }
}